// Round 11
// baseline (1114.430 us; speedup 1.0000x reference)
//
#include <hip/hip_runtime.h>
#include <math.h>

#define T_STEPS 512
#define IN_DIM  32
#define H       64
#define NB      1     // batch rows per block

typedef _Float16 h2 __attribute__((ext_vector_type(2)));

#if __has_builtin(__builtin_amdgcn_fdot2)
__device__ __forceinline__ float fdot2(h2 a, h2 b, float c) {
    return __builtin_amdgcn_fdot2(a, b, c, false);
}
#else
__device__ __forceinline__ float fdot2(h2 a, h2 b, float c) {
    return c + (float)a.x * (float)b.x + (float)a.y * (float)b.y;
}
#endif

__device__ __forceinline__ h2 bc2(unsigned u) { return __builtin_bit_cast(h2, u); }
__device__ __forceinline__ h2 mk2(_Float16 a, _Float16 b) { h2 r; r.x = a; r.y = b; return r; }

__device__ __forceinline__ float sigmoid_f(float x) {
    float e = __expf(-x);
    return __builtin_amdgcn_rcpf(1.0f + e);
}
__device__ __forceinline__ float tanh_f(float x) {
    float e = __expf(2.0f * x);
    return 1.0f - 2.0f * __builtin_amdgcn_rcpf(1.0f + e);
}

// Wave-specialized pipelined 2-layer LSTM, f16-packed operands, f32 accumulate.
//   waves 0-3 (tid<256): layer 0, gate row g = tid
//   waves 4-7          : layer 1, gate row g = tid-256
// Layer 1 runs one timestep behind layer 0. 2 barriers/iter.
// NB=1, grid=1024: 4 blocks/CU queued, ~2 resident for barrier overlap.
// LDS operands read as uint4 and bit-cast to h2 so fdot2 consumes them
// directly (no v_pack repack per fdot2).
__launch_bounds__(512, 4)
__global__ void lstm_forecast_kernel(
    const float* __restrict__ seq, const int* __restrict__ line_id,
    const float* __restrict__ embed,
    const float* __restrict__ w_ih0, const float* __restrict__ w_hh0,
    const float* __restrict__ b_ih0, const float* __restrict__ b_hh0,
    const float* __restrict__ w_ih1, const float* __restrict__ w_hh1,
    const float* __restrict__ b_ih1, const float* __restrict__ b_hh1,
    const float* __restrict__ w1, const float* __restrict__ b1,
    const float* __restrict__ w2, const float* __restrict__ b2,
    float* __restrict__ out)
{
    const int tid = threadIdx.x;
    const bool isA = (tid < 256);
    const int g    = tid & 255;
    const int b0   = blockIdx.x;          // one batch row per block

    __shared__ __align__(16) h2 x_lds[IN_DIM / 2];   // f16 x       (64 B)
    __shared__ __align__(16) h2 h0_lds[H / 2];       // f16 h0     (128 B)
    __shared__ __align__(16) h2 h1_lds[H / 2];       // f16 h1     (128 B)
    __shared__ __align__(16) float gates0_lds[4 * H];
    __shared__ __align__(16) float gates1_lds[4 * H];

    // ---- per-thread weight rows, f16-packed in VGPRs ----
    // A: wih[0..15] = w_ih0 row (32 w), whh[0..31] = w_hh0 row (64 w)
    // B: wih[0..31] = w_ih1 row (64 w), whh[0..31] = w_hh1 row (64 w)
    h2 wih[32], whh[32];
    float bias;
    if (isA) {
        const float4* p = reinterpret_cast<const float4*>(w_ih0 + (size_t)g * IN_DIM);
        #pragma unroll
        for (int j = 0; j < 8; ++j) {
            float4 v = p[j];
            wih[2*j+0] = mk2((_Float16)v.x, (_Float16)v.y);
            wih[2*j+1] = mk2((_Float16)v.z, (_Float16)v.w);
        }
        const float4* q = reinterpret_cast<const float4*>(w_hh0 + (size_t)g * H);
        #pragma unroll
        for (int j = 0; j < 16; ++j) {
            float4 v = q[j];
            whh[2*j+0] = mk2((_Float16)v.x, (_Float16)v.y);
            whh[2*j+1] = mk2((_Float16)v.z, (_Float16)v.w);
        }
        bias = b_ih0[g] + b_hh0[g];
    } else {
        const float4* p = reinterpret_cast<const float4*>(w_ih1 + (size_t)g * H);
        #pragma unroll
        for (int j = 0; j < 16; ++j) {
            float4 v = p[j];
            wih[2*j+0] = mk2((_Float16)v.x, (_Float16)v.y);
            wih[2*j+1] = mk2((_Float16)v.z, (_Float16)v.w);
        }
        const float4* q = reinterpret_cast<const float4*>(w_hh1 + (size_t)g * H);
        #pragma unroll
        for (int j = 0; j < 16; ++j) {
            float4 v = q[j];
            whh[2*j+0] = mk2((_Float16)v.x, (_Float16)v.y);
            whh[2*j+1] = mk2((_Float16)v.z, (_Float16)v.w);
        }
        bias = b_ih1[g] + b_hh1[g];
    }

    // init h state (f16 zeros)
    if (isA) { if (g < H / 2) h0_lds[g] = mk2((_Float16)0.f, (_Float16)0.f); }
    else     { if (g < H / 2) h1_lds[g] = mk2((_Float16)0.f, (_Float16)0.f); }

    // x stagers: A threads g in [128, 128+16): one float2 pair each
    const int sj = g - 128;
    const bool stager = isA && (sj >= 0) && (sj < IN_DIM / 2);
    const int sp = sj & 15;
    const float2* seq2 = reinterpret_cast<const float2*>(seq);
    const size_t sbase = (size_t)b0 * T_STEPS * (IN_DIM / 2) + sp;
    float2 xreg = make_float2(0.f, 0.f);
    if (stager) {
        float2 v0 = seq2[sbase];                       // t = 0
        x_lds[sp] = mk2((_Float16)v0.x, (_Float16)v0.y);
        xreg = seq2[sbase + (IN_DIM / 2)];             // t = 1
    }

    float c = 0.0f;            // c0 for A updaters, c1 for B updaters
    const int uk = g & 63;     // update role (g < 64): hidden component
    __syncthreads();

    // iteration t: layer-0 step t (A, t<512) and layer-1 step t-1 (B, t>=1)
    #pragma unroll 1
    for (int t = 0; t <= T_STEPS; ++t) {
        // ---- gate phase ----
        if (isA) {
            if (t < T_STEPS) {
                float a = bias;
                const uint4* xv = reinterpret_cast<const uint4*>(&x_lds[0]);  // 4 x uint4
                #pragma unroll
                for (int j = 0; j < 4; ++j) {
                    uint4 u = xv[j];
                    a = fdot2(wih[4*j+0], bc2(u.x), a);
                    a = fdot2(wih[4*j+1], bc2(u.y), a);
                    a = fdot2(wih[4*j+2], bc2(u.z), a);
                    a = fdot2(wih[4*j+3], bc2(u.w), a);
                }
                const uint4* hv = reinterpret_cast<const uint4*>(&h0_lds[0]); // 8 x uint4
                #pragma unroll
                for (int j = 0; j < 8; ++j) {
                    uint4 u = hv[j];
                    a = fdot2(whh[4*j+0], bc2(u.x), a);
                    a = fdot2(whh[4*j+1], bc2(u.y), a);
                    a = fdot2(whh[4*j+2], bc2(u.z), a);
                    a = fdot2(whh[4*j+3], bc2(u.w), a);
                }
                gates0_lds[g] = a;
            }
        } else {
            if (t >= 1) {
                float a = bias;
                const uint4* h0v = reinterpret_cast<const uint4*>(&h0_lds[0]);
                #pragma unroll
                for (int j = 0; j < 8; ++j) {
                    uint4 u = h0v[j];
                    a = fdot2(wih[4*j+0], bc2(u.x), a);
                    a = fdot2(wih[4*j+1], bc2(u.y), a);
                    a = fdot2(wih[4*j+2], bc2(u.z), a);
                    a = fdot2(wih[4*j+3], bc2(u.w), a);
                }
                const uint4* h1v = reinterpret_cast<const uint4*>(&h1_lds[0]);
                #pragma unroll
                for (int j = 0; j < 8; ++j) {
                    uint4 u = h1v[j];
                    a = fdot2(whh[4*j+0], bc2(u.x), a);
                    a = fdot2(whh[4*j+1], bc2(u.y), a);
                    a = fdot2(whh[4*j+2], bc2(u.z), a);
                    a = fdot2(whh[4*j+3], bc2(u.w), a);
                }
                gates1_lds[g] = a;
            }
        }
        __syncthreads();

        // ---- update phase ----
        if (isA) {
            if (t < T_STEPS && g < H) {
                float ig = sigmoid_f(gates0_lds[       uk]);
                float fg = sigmoid_f(gates0_lds[  H  + uk]);
                float gg =    tanh_f(gates0_lds[2*H  + uk]);
                float og = sigmoid_f(gates0_lds[3*H  + uk]);
                c = fmaf(fg, c, ig * gg);
                ((_Float16*)h0_lds)[uk] = (_Float16)(og * tanh_f(c));
            }
            if (stager && (t + 1) < T_STEPS) {
                x_lds[sp] = mk2((_Float16)xreg.x, (_Float16)xreg.y);
                if ((t + 2) < T_STEPS)
                    xreg = seq2[sbase + (size_t)(t + 2) * (IN_DIM / 2)];
            }
        } else {
            if (t >= 1 && g < H) {
                float ig = sigmoid_f(gates1_lds[       uk]);
                float fg = sigmoid_f(gates1_lds[  H  + uk]);
                float gg =    tanh_f(gates1_lds[2*H  + uk]);
                float og = sigmoid_f(gates1_lds[3*H  + uk]);
                c = fmaf(fg, c, ig * gg);
                ((_Float16*)h1_lds)[uk] = (_Float16)(og * tanh_f(c));
            }
        }
        __syncthreads();
    }

    // ---- head: fc1 = relu([h1, emb] @ w1.T + b1); out = fc1 @ w2.T + b2 ----
    if (tid < H) {
        float a = b1[uk];
        #pragma unroll
        for (int j = 0; j < H; ++j)
            a = fmaf(w1[uk*(H+8) + j], (float)((const _Float16*)h1_lds)[j], a);
        const int lid = line_id[b0];
        #pragma unroll
        for (int e = 0; e < 8; ++e)
            a = fmaf(w1[uk*(H+8) + H + e], embed[lid*8 + e], a);
        gates0_lds[uk] = fmaxf(a, 0.0f);   // fc1 buffer
    }
    __syncthreads();
    if (tid < 5) {
        float o = b2[tid];
        #pragma unroll
        for (int j = 0; j < H; ++j)
            o = fmaf(w2[tid*H + j], gates0_lds[j], o);
        out[b0 * 5 + tid] = o;
    }
}

extern "C" void kernel_launch(void* const* d_in, const int* in_sizes, int n_in,
                              void* d_out, int out_size, void* d_ws, size_t ws_size,
                              hipStream_t stream) {
    const float* seq     = (const float*)d_in[0];
    const int*   line_id = (const int*)  d_in[1];
    const float* embed   = (const float*)d_in[2];
    const float* w_ih0   = (const float*)d_in[3];
    const float* w_hh0   = (const float*)d_in[4];
    const float* b_ih0   = (const float*)d_in[5];
    const float* b_hh0   = (const float*)d_in[6];
    const float* w_ih1   = (const float*)d_in[7];
    const float* w_hh1   = (const float*)d_in[8];
    const float* b_ih1   = (const float*)d_in[9];
    const float* b_hh1   = (const float*)d_in[10];
    const float* w1      = (const float*)d_in[11];
    const float* b1      = (const float*)d_in[12];
    const float* w2      = (const float*)d_in[13];
    const float* b2      = (const float*)d_in[14];
    float* out = (float*)d_out;

    lstm_forecast_kernel<<<dim3(1024), dim3(512), 0, stream>>>(
        seq, line_id, embed,
        w_ih0, w_hh0, b_ih0, b_hh0,
        w_ih1, w_hh1, b_ih1, b_hh1,
        w1, b1, w2, b2, out);
}

// Round 12
// 666.520 us; speedup vs baseline: 1.6720x; 1.6720x over previous
//
#include <hip/hip_runtime.h>
#include <math.h>

#define T_STEPS 512
#define IN_DIM  32
#define H       64
#define NBATCH  16     // batch rows per block; grid = 1024/16 = 64
#define PK0     100    // padded K for B0 rows (x: k 0-31 | h0: k 32-95); 200 B, 8B-aligned rows
#define PK1     132    // padded K for B1 rows (h0: k 0-63 | h1: k 64-127); 264 B

typedef _Float16 half8 __attribute__((ext_vector_type(8)));
typedef _Float16 half4 __attribute__((ext_vector_type(4)));
typedef float    f32x4 __attribute__((ext_vector_type(4)));

__device__ __forceinline__ float sigmoid_f(float x) {
    float e = __expf(-x);
    return __builtin_amdgcn_rcpf(1.0f + e);
}
__device__ __forceinline__ float tanh_f(float x) {
    float e = __expf(2.0f * x);
    return 1.0f - 2.0f * __builtin_amdgcn_rcpf(1.0f + e);
}

// A-fragment for v_mfma_f32_16x16x32_f16 from row-major f32 W (row stride K):
// lane l holds A[m][kb+{0..3}] in elems 0-3, A[m][kb+16+{0..3}] in elems 4-7,
// m = l&15, kb = c0 + (l>>4)*4  (c0 = K-tile column offset).
__device__ __forceinline__ half8 load_afrag(const float* __restrict__ W, int K,
                                            int m, int kb) {
    const float4 a = *reinterpret_cast<const float4*>(W + (size_t)m * K + kb);
    const float4 b = *reinterpret_cast<const float4*>(W + (size_t)m * K + kb + 16);
    half8 r;
    r[0] = (_Float16)a.x; r[1] = (_Float16)a.y; r[2] = (_Float16)a.z; r[3] = (_Float16)a.w;
    r[4] = (_Float16)b.x; r[5] = (_Float16)b.y; r[6] = (_Float16)b.z; r[7] = (_Float16)b.w;
    return r;
}

// B-fragment: LDS stores operand as [n][k] rows (n = batch col). Lane l needs
// B[k0+{0..3}][n] and B[k0+16+{0..3}][n]; rowbase = &lds[n][0], k0 = ktile*32+(l>>4)*4.
__device__ __forceinline__ half8 read_bfrag(const _Float16* rowbase, int k0) {
    uint2 lo = *reinterpret_cast<const uint2*>(rowbase + k0);
    uint2 hi = *reinterpret_cast<const uint2*>(rowbase + k0 + 16);
    uint4 u; u.x = lo.x; u.y = lo.y; u.z = hi.x; u.w = hi.y;
    return __builtin_bit_cast(half8, u);
}

// Pipelined 2-layer LSTM on MFMA. Waves 0-3: layer 0 (h-rows [16w,16w+16) via
// IFGO M-tiles {w, w+4, w+8, w+12}); waves 4-7: layer 1, one step behind.
// C/D layout (HW-verified): col=lane&15 (batch), row=(lane>>4)*4+reg (h-idx)
// -> i,f,g,o for one (h-idx,batch) cell are lane-local across the 4 tiles.
// One barrier per iteration (reads from buf[t&1], writes to buf[~t&1]).
__launch_bounds__(512, 1)
__global__ void lstm_forecast_kernel(
    const float* __restrict__ seq, const int* __restrict__ line_id,
    const float* __restrict__ embed,
    const float* __restrict__ w_ih0, const float* __restrict__ w_hh0,
    const float* __restrict__ b_ih0, const float* __restrict__ b_hh0,
    const float* __restrict__ w_ih1, const float* __restrict__ w_hh1,
    const float* __restrict__ b_ih1, const float* __restrict__ b_hh1,
    const float* __restrict__ w1, const float* __restrict__ b1,
    const float* __restrict__ w2, const float* __restrict__ b2,
    float* __restrict__ out)
{
    const int tid  = threadIdx.x;
    const int lane = tid & 63;
    const int wid  = tid >> 6;
    const int lmod = lane & 15;        // A m-idx / B-C-D col (batch)
    const int lgrp = lane >> 4;        // 16-lane group
    const int rowbase = lgrp * 4;      // C/D row base within a tile
    const int kb = lgrp * 4;           // fragment k base within a K-tile
    const int b0 = blockIdx.x * NBATCH;

    __shared__ _Float16 B0[2][NBATCH][PK0];
    __shared__ _Float16 B1[2][NBATCH][PK1];
    __shared__ float fc1_lds[NBATCH][H];

    const bool isL0 = (wid < 4);
    const int  w    = isL0 ? wid : wid - 4;

    // ---- persistent A-fragments (weights) + per-lane bias ----
    half8 Af[4][4];
    f32x4 bv[4];
    #pragma unroll
    for (int G = 0; G < 4; ++G) {
        const int m = (w + 4 * G) * 16 + lmod;
        const int rw = (w + 4 * G) * 16 + rowbase;
        if (isL0) {
            Af[G][0] = load_afrag(w_ih0, IN_DIM, m, kb);
            Af[G][1] = load_afrag(w_hh0, H, m, kb);
            Af[G][2] = load_afrag(w_hh0, H, m, 32 + kb);
            Af[G][3] = Af[G][2];  // unused
            f32x4 b;
            #pragma unroll
            for (int r = 0; r < 4; ++r) b[r] = b_ih0[rw + r] + b_hh0[rw + r];
            bv[G] = b;
        } else {
            Af[G][0] = load_afrag(w_ih1, H, m, kb);
            Af[G][1] = load_afrag(w_ih1, H, m, 32 + kb);
            Af[G][2] = load_afrag(w_hh1, H, m, kb);
            Af[G][3] = load_afrag(w_hh1, H, m, 32 + kb);
            f32x4 b;
            #pragma unroll
            for (int r = 0; r < 4; ++r) b[r] = b_ih1[rw + r] + b_hh1[rw + r];
            bv[G] = b;
        }
    }

    float cst[4] = {0.f, 0.f, 0.f, 0.f};   // cell state, rows rowbase..+3, col lmod

    // ---- zero init h0 (B0[0] k 32-95) and h1[-1] (B1[1] k 64-127); stage x[0] ----
    {
        const int zn = tid >> 5;
        const int zk = (tid & 31) * 2;
        *reinterpret_cast<unsigned*>(&B0[0][zn][32 + zk]) = 0u;
        *reinterpret_cast<unsigned*>(&B1[1][zn][64 + zk]) = 0u;
        B0[0][zn][(tid & 31)] =
            (_Float16)seq[((size_t)(b0 + zn) * T_STEPS + 0) * IN_DIM + (tid & 31)];
    }
    __syncthreads();

    const int sn = tid >> 5, si = tid & 31;   // x-staging role (all threads)
    const int hidx0 = w * 16 + rowbase;       // this lane's first h-row

    #pragma unroll 1
    for (int t = 0; t <= T_STEPS; ++t) {
        const int cur = t & 1, nxt = cur ^ 1;

        // issue x[t+1] global load early (hidden under MFMA/nonlin)
        float xval = 0.f;
        if (t + 1 < T_STEPS)
            xval = seq[((size_t)(b0 + sn) * T_STEPS + (t + 1)) * IN_DIM + si];

        if (isL0) {
            if (t < T_STEPS) {
                const _Float16* bb = &B0[cur][lmod][0];
                const half8 Bx  = read_bfrag(bb, kb);
                const half8 Bh0a = read_bfrag(bb, 32 + kb);
                const half8 Bh0b = read_bfrag(bb, 64 + kb);
                f32x4 C0 = bv[0], C1 = bv[1], C2 = bv[2], C3 = bv[3];
                C0 = __builtin_amdgcn_mfma_f32_16x16x32_f16(Af[0][0], Bx,   C0, 0, 0, 0);
                C0 = __builtin_amdgcn_mfma_f32_16x16x32_f16(Af[0][1], Bh0a, C0, 0, 0, 0);
                C0 = __builtin_amdgcn_mfma_f32_16x16x32_f16(Af[0][2], Bh0b, C0, 0, 0, 0);
                C1 = __builtin_amdgcn_mfma_f32_16x16x32_f16(Af[1][0], Bx,   C1, 0, 0, 0);
                C1 = __builtin_amdgcn_mfma_f32_16x16x32_f16(Af[1][1], Bh0a, C1, 0, 0, 0);
                C1 = __builtin_amdgcn_mfma_f32_16x16x32_f16(Af[1][2], Bh0b, C1, 0, 0, 0);
                C2 = __builtin_amdgcn_mfma_f32_16x16x32_f16(Af[2][0], Bx,   C2, 0, 0, 0);
                C2 = __builtin_amdgcn_mfma_f32_16x16x32_f16(Af[2][1], Bh0a, C2, 0, 0, 0);
                C2 = __builtin_amdgcn_mfma_f32_16x16x32_f16(Af[2][2], Bh0b, C2, 0, 0, 0);
                C3 = __builtin_amdgcn_mfma_f32_16x16x32_f16(Af[3][0], Bx,   C3, 0, 0, 0);
                C3 = __builtin_amdgcn_mfma_f32_16x16x32_f16(Af[3][1], Bh0a, C3, 0, 0, 0);
                C3 = __builtin_amdgcn_mfma_f32_16x16x32_f16(Af[3][2], Bh0b, C3, 0, 0, 0);
                half4 hh;
                #pragma unroll
                for (int r = 0; r < 4; ++r) {
                    float ig = sigmoid_f(C0[r]);
                    float fg = sigmoid_f(C1[r]);
                    float gg = tanh_f(C2[r]);
                    float og = sigmoid_f(C3[r]);
                    cst[r] = fg * cst[r] + ig * gg;
                    hh[r] = (_Float16)(og * tanh_f(cst[r]));
                }
                const uint2 hu = __builtin_bit_cast(uint2, hh);
                *reinterpret_cast<uint2*>(&B0[nxt][lmod][32 + hidx0]) = hu;
                *reinterpret_cast<uint2*>(&B1[nxt][lmod][hidx0]) = hu;
            }
        } else {
            if (t >= 1) {
                const _Float16* bb = &B1[cur][lmod][0];
                const half8 Bh0a = read_bfrag(bb, kb);
                const half8 Bh0b = read_bfrag(bb, 32 + kb);
                const half8 Bh1a = read_bfrag(bb, 64 + kb);
                const half8 Bh1b = read_bfrag(bb, 96 + kb);
                f32x4 C0 = bv[0], C1 = bv[1], C2 = bv[2], C3 = bv[3];
                C0 = __builtin_amdgcn_mfma_f32_16x16x32_f16(Af[0][0], Bh0a, C0, 0, 0, 0);
                C0 = __builtin_amdgcn_mfma_f32_16x16x32_f16(Af[0][1], Bh0b, C0, 0, 0, 0);
                C0 = __builtin_amdgcn_mfma_f32_16x16x32_f16(Af[0][2], Bh1a, C0, 0, 0, 0);
                C0 = __builtin_amdgcn_mfma_f32_16x16x32_f16(Af[0][3], Bh1b, C0, 0, 0, 0);
                C1 = __builtin_amdgcn_mfma_f32_16x16x32_f16(Af[1][0], Bh0a, C1, 0, 0, 0);
                C1 = __builtin_amdgcn_mfma_f32_16x16x32_f16(Af[1][1], Bh0b, C1, 0, 0, 0);
                C1 = __builtin_amdgcn_mfma_f32_16x16x32_f16(Af[1][2], Bh1a, C1, 0, 0, 0);
                C1 = __builtin_amdgcn_mfma_f32_16x16x32_f16(Af[1][3], Bh1b, C1, 0, 0, 0);
                C2 = __builtin_amdgcn_mfma_f32_16x16x32_f16(Af[2][0], Bh0a, C2, 0, 0, 0);
                C2 = __builtin_amdgcn_mfma_f32_16x16x32_f16(Af[2][1], Bh0b, C2, 0, 0, 0);
                C2 = __builtin_amdgcn_mfma_f32_16x16x32_f16(Af[2][2], Bh1a, C2, 0, 0, 0);
                C2 = __builtin_amdgcn_mfma_f32_16x16x32_f16(Af[2][3], Bh1b, C2, 0, 0, 0);
                C3 = __builtin_amdgcn_mfma_f32_16x16x32_f16(Af[3][0], Bh0a, C3, 0, 0, 0);
                C3 = __builtin_amdgcn_mfma_f32_16x16x32_f16(Af[3][1], Bh0b, C3, 0, 0, 0);
                C3 = __builtin_amdgcn_mfma_f32_16x16x32_f16(Af[3][2], Bh1a, C3, 0, 0, 0);
                C3 = __builtin_amdgcn_mfma_f32_16x16x32_f16(Af[3][3], Bh1b, C3, 0, 0, 0);
                half4 hh;
                #pragma unroll
                for (int r = 0; r < 4; ++r) {
                    float ig = sigmoid_f(C0[r]);
                    float fg = sigmoid_f(C1[r]);
                    float gg = tanh_f(C2[r]);
                    float og = sigmoid_f(C3[r]);
                    cst[r] = fg * cst[r] + ig * gg;
                    hh[r] = (_Float16)(og * tanh_f(cst[r]));
                }
                const uint2 hu = __builtin_bit_cast(uint2, hh);
                *reinterpret_cast<uint2*>(&B1[nxt][lmod][64 + hidx0]) = hu;
            }
        }

        // stage x[t+1] into B0[nxt] (k 0-31; disjoint from h region)
        if (t + 1 < T_STEPS) B0[nxt][sn][si] = (_Float16)xval;
        __syncthreads();
    }

    // ---- head. h1_last = h1[T-1] lives in B1[(T+1)&1] = B1[1], k 64-127 ----
    {
        const int un = tid & 15;          // batch row
        const int uk0 = tid >> 4;         // 0..31; handle uk0 and uk0+32
        const int lid = line_id[b0 + un];
        #pragma unroll
        for (int hh = 0; hh < 2; ++hh) {
            const int u = uk0 + 32 * hh;
            float a = b1[u];
            #pragma unroll
            for (int j = 0; j < H; ++j)
                a = fmaf(w1[u * (H + 8) + j], (float)B1[1][un][64 + j], a);
            #pragma unroll
            for (int e = 0; e < 8; ++e)
                a = fmaf(w1[u * (H + 8) + H + e], embed[lid * 8 + e], a);
            fc1_lds[un][u] = fmaxf(a, 0.f);
        }
    }
    __syncthreads();
    if (tid < NBATCH * 5) {
        const int n2 = tid / 5, q = tid - 5 * n2;
        float o = b2[q];
        #pragma unroll
        for (int j = 0; j < H; ++j)
            o = fmaf(w2[q * H + j], fc1_lds[n2][j], o);
        out[(b0 + n2) * 5 + q] = o;
    }
}

extern "C" void kernel_launch(void* const* d_in, const int* in_sizes, int n_in,
                              void* d_out, int out_size, void* d_ws, size_t ws_size,
                              hipStream_t stream) {
    const float* seq     = (const float*)d_in[0];
    const int*   line_id = (const int*)  d_in[1];
    const float* embed   = (const float*)d_in[2];
    const float* w_ih0   = (const float*)d_in[3];
    const float* w_hh0   = (const float*)d_in[4];
    const float* b_ih0   = (const float*)d_in[5];
    const float* b_hh0   = (const float*)d_in[6];
    const float* w_ih1   = (const float*)d_in[7];
    const float* w_hh1   = (const float*)d_in[8];
    const float* b_ih1   = (const float*)d_in[9];
    const float* b_hh1   = (const float*)d_in[10];
    const float* w1      = (const float*)d_in[11];
    const float* b1      = (const float*)d_in[12];
    const float* w2      = (const float*)d_in[13];
    const float* b2      = (const float*)d_in[14];
    float* out = (float*)d_out;

    lstm_forecast_kernel<<<dim3(1024 / NBATCH), dim3(512), 0, stream>>>(
        seq, line_id, embed,
        w_ih0, w_hh0, b_ih0, b_hh0,
        w_ih1, w_hh1, b_ih1, b_hh1,
        w1, b1, w2, b2, out);
}

// Round 14
// 579.574 us; speedup vs baseline: 1.9228x; 1.1500x over previous
//
#include <hip/hip_runtime.h>
#include <math.h>

#define T_STEPS 512
#define IN_DIM  32
#define H       64
#define NBATCH  16     // batch rows per block; grid = 1024/16 = 64
#define PK0     100    // padded K for B0 rows (x: k 0-31 | h0: k 32-95)
#define PK1     132    // padded K for B1 rows (h0: k 0-63 | h1: k 64-127)

typedef _Float16 half8 __attribute__((ext_vector_type(8)));
typedef _Float16 half4 __attribute__((ext_vector_type(4)));
typedef float    f32x4 __attribute__((ext_vector_type(4)));

__device__ __forceinline__ float sigmoid_f(float x) {
    float e = __expf(-x);
    return __builtin_amdgcn_rcpf(1.0f + e);
}
__device__ __forceinline__ float tanh_f(float x) {
    float e = __expf(2.0f * x);
    return 1.0f - 2.0f * __builtin_amdgcn_rcpf(1.0f + e);
}

// A-fragment for v_mfma_f32_16x16x32_f16 from row-major f32 W (row stride K):
// lane l holds A[m][kb+{0..3}] elems 0-3, A[m][kb+16+{0..3}] elems 4-7,
// m = l&15, kb = c0 + (l>>4)*4.
__device__ __forceinline__ half8 load_afrag(const float* __restrict__ W, int K,
                                            int m, int kb) {
    const float4 a = *reinterpret_cast<const float4*>(W + (size_t)m * K + kb);
    const float4 b = *reinterpret_cast<const float4*>(W + (size_t)m * K + kb + 16);
    half8 r;
    r[0] = (_Float16)a.x; r[1] = (_Float16)a.y; r[2] = (_Float16)a.z; r[3] = (_Float16)a.w;
    r[4] = (_Float16)b.x; r[5] = (_Float16)b.y; r[6] = (_Float16)b.z; r[7] = (_Float16)b.w;
    return r;
}

// B-fragment: LDS stores operand as [n][k] rows. Lane l reads B[k0+{0..3}][n]
// and B[k0+16+{0..3}][n]; rowbase = &lds[n][0], k0 = ktile*32 + (l>>4)*4.
__device__ __forceinline__ half8 read_bfrag(const _Float16* rowbase, int k0) {
    uint2 lo = *reinterpret_cast<const uint2*>(rowbase + k0);
    uint2 hi = *reinterpret_cast<const uint2*>(rowbase + k0 + 16);
    uint4 u; u.x = lo.x; u.y = lo.y; u.z = hi.x; u.w = hi.y;
    return __builtin_bit_cast(half8, u);
}

// Pipelined 2-layer LSTM on MFMA. Waves 0-3: layer 0 (h-rows [16w,16w+16) via
// IFGO M-tiles {w, w+4, w+8, w+12}); waves 4-7: layer 1, one step behind.
// C/D layout (HW-verified): col=lane&15 (batch), row=(lane>>4)*4+reg (h-idx).
// One barrier per iteration.
// R13: (1) x[t+1] carried in a register across iterations -> LDS write at
// iteration START (HBM latency off the critical path); (2) MFMA accumulation
// split into two depth-2 chains + vector add (was depth 3-4 serial).
__launch_bounds__(512, 1)
__global__ void lstm_forecast_kernel(
    const float* __restrict__ seq, const int* __restrict__ line_id,
    const float* __restrict__ embed,
    const float* __restrict__ w_ih0, const float* __restrict__ w_hh0,
    const float* __restrict__ b_ih0, const float* __restrict__ b_hh0,
    const float* __restrict__ w_ih1, const float* __restrict__ w_hh1,
    const float* __restrict__ b_ih1, const float* __restrict__ b_hh1,
    const float* __restrict__ w1, const float* __restrict__ b1,
    const float* __restrict__ w2, const float* __restrict__ b2,
    float* __restrict__ out)
{
    const int tid  = threadIdx.x;
    const int lane = tid & 63;
    const int wid  = tid >> 6;
    const int lmod = lane & 15;        // A m-idx / B-C-D col (batch)
    const int lgrp = lane >> 4;        // 16-lane group
    const int rowbase = lgrp * 4;      // C/D row base within a tile
    const int kb = lgrp * 4;           // fragment k base within a K-tile
    const int b0 = blockIdx.x * NBATCH;

    __shared__ _Float16 B0[2][NBATCH][PK0];
    __shared__ _Float16 B1[2][NBATCH][PK1];
    __shared__ float fc1_lds[NBATCH][H];

    const bool isL0 = (wid < 4);
    const int  w    = isL0 ? wid : wid - 4;

    // ---- persistent A-fragments (weights) + per-lane bias ----
    half8 Af[4][4];
    f32x4 bv[4];
    #pragma unroll
    for (int G = 0; G < 4; ++G) {
        const int m = (w + 4 * G) * 16 + lmod;
        const int rw = (w + 4 * G) * 16 + rowbase;
        if (isL0) {
            Af[G][0] = load_afrag(w_ih0, IN_DIM, m, kb);
            Af[G][1] = load_afrag(w_hh0, H, m, kb);
            Af[G][2] = load_afrag(w_hh0, H, m, 32 + kb);
            Af[G][3] = Af[G][2];  // unused
            f32x4 b;
            #pragma unroll
            for (int r = 0; r < 4; ++r) b[r] = b_ih0[rw + r] + b_hh0[rw + r];
            bv[G] = b;
        } else {
            Af[G][0] = load_afrag(w_ih1, H, m, kb);
            Af[G][1] = load_afrag(w_ih1, H, m, 32 + kb);
            Af[G][2] = load_afrag(w_hh1, H, m, kb);
            Af[G][3] = load_afrag(w_hh1, H, m, 32 + kb);
            f32x4 b;
            #pragma unroll
            for (int r = 0; r < 4; ++r) b[r] = b_ih1[rw + r] + b_hh1[rw + r];
            bv[G] = b;
        }
    }

    float cst[4] = {0.f, 0.f, 0.f, 0.f};   // cell state

    // ---- zero init h0 / h1[-1]; stage x[0]; preload x[1] into register ----
    const int sn = tid >> 5, si = tid & 31;
    const size_t sbase = ((size_t)(b0 + sn) * T_STEPS) * IN_DIM + si;
    {
        const int zk = si * 2;
        *reinterpret_cast<unsigned*>(&B0[0][sn][32 + zk]) = 0u;
        *reinterpret_cast<unsigned*>(&B1[1][sn][64 + zk]) = 0u;
        B0[0][sn][si] = (_Float16)seq[sbase];
    }
    float xv1 = seq[sbase + IN_DIM];   // x[1]
    __syncthreads();

    const int hidx0 = w * 16 + rowbase;
    const f32x4 zf = {0.f, 0.f, 0.f, 0.f};

    #pragma unroll 1
    for (int t = 0; t <= T_STEPS; ++t) {
        const int cur = t & 1, nxt = cur ^ 1;

        // (1) write x[t+1] (already in register) at iteration START;
        //     then issue x[t+2] load -- a full iteration to cover HBM latency.
        if (t + 1 < T_STEPS) B0[nxt][sn][si] = (_Float16)xv1;
        float xnew = 0.f;
        if (t + 2 < T_STEPS) xnew = seq[sbase + (size_t)(t + 2) * IN_DIM];

        if (isL0) {
            if (t < T_STEPS) {
                const _Float16* bb = &B0[cur][lmod][0];
                const half8 Bx   = read_bfrag(bb, kb);
                const half8 Bh0a = read_bfrag(bb, 32 + kb);
                const half8 Bh0b = read_bfrag(bb, 64 + kb);
                // (2) two independent depth-2 chains per tile + vector add
                f32x4 A0 = bv[0], A1 = bv[1], A2 = bv[2], A3 = bv[3];
                f32x4 D0 = zf, D1 = zf, D2 = zf, D3 = zf;
                A0 = __builtin_amdgcn_mfma_f32_16x16x32_f16(Af[0][0], Bx,   A0, 0, 0, 0);
                A1 = __builtin_amdgcn_mfma_f32_16x16x32_f16(Af[1][0], Bx,   A1, 0, 0, 0);
                A2 = __builtin_amdgcn_mfma_f32_16x16x32_f16(Af[2][0], Bx,   A2, 0, 0, 0);
                A3 = __builtin_amdgcn_mfma_f32_16x16x32_f16(Af[3][0], Bx,   A3, 0, 0, 0);
                D0 = __builtin_amdgcn_mfma_f32_16x16x32_f16(Af[0][1], Bh0a, D0, 0, 0, 0);
                D1 = __builtin_amdgcn_mfma_f32_16x16x32_f16(Af[1][1], Bh0a, D1, 0, 0, 0);
                D2 = __builtin_amdgcn_mfma_f32_16x16x32_f16(Af[2][1], Bh0a, D2, 0, 0, 0);
                D3 = __builtin_amdgcn_mfma_f32_16x16x32_f16(Af[3][1], Bh0a, D3, 0, 0, 0);
                A0 = __builtin_amdgcn_mfma_f32_16x16x32_f16(Af[0][2], Bh0b, A0, 0, 0, 0);
                A1 = __builtin_amdgcn_mfma_f32_16x16x32_f16(Af[1][2], Bh0b, A1, 0, 0, 0);
                A2 = __builtin_amdgcn_mfma_f32_16x16x32_f16(Af[2][2], Bh0b, A2, 0, 0, 0);
                A3 = __builtin_amdgcn_mfma_f32_16x16x32_f16(Af[3][2], Bh0b, A3, 0, 0, 0);
                const f32x4 C0 = A0 + D0, C1 = A1 + D1, C2 = A2 + D2, C3 = A3 + D3;
                half4 hh;
                #pragma unroll
                for (int r = 0; r < 4; ++r) {
                    float ig = sigmoid_f(C0[r]);
                    float fg = sigmoid_f(C1[r]);
                    float gg = tanh_f(C2[r]);
                    float og = sigmoid_f(C3[r]);
                    cst[r] = fg * cst[r] + ig * gg;
                    hh[r] = (_Float16)(og * tanh_f(cst[r]));
                }
                const uint2 hu = __builtin_bit_cast(uint2, hh);
                *reinterpret_cast<uint2*>(&B0[nxt][lmod][32 + hidx0]) = hu;
                *reinterpret_cast<uint2*>(&B1[nxt][lmod][hidx0]) = hu;
            }
        } else {
            if (t >= 1) {
                const _Float16* bb = &B1[cur][lmod][0];
                const half8 Bh0a = read_bfrag(bb, kb);
                const half8 Bh0b = read_bfrag(bb, 32 + kb);
                const half8 Bh1a = read_bfrag(bb, 64 + kb);
                const half8 Bh1b = read_bfrag(bb, 96 + kb);
                f32x4 A0 = bv[0], A1 = bv[1], A2 = bv[2], A3 = bv[3];
                f32x4 D0 = zf, D1 = zf, D2 = zf, D3 = zf;
                A0 = __builtin_amdgcn_mfma_f32_16x16x32_f16(Af[0][0], Bh0a, A0, 0, 0, 0);
                A1 = __builtin_amdgcn_mfma_f32_16x16x32_f16(Af[1][0], Bh0a, A1, 0, 0, 0);
                A2 = __builtin_amdgcn_mfma_f32_16x16x32_f16(Af[2][0], Bh0a, A2, 0, 0, 0);
                A3 = __builtin_amdgcn_mfma_f32_16x16x32_f16(Af[3][0], Bh0a, A3, 0, 0, 0);
                D0 = __builtin_amdgcn_mfma_f32_16x16x32_f16(Af[0][2], Bh1a, D0, 0, 0, 0);
                D1 = __builtin_amdgcn_mfma_f32_16x16x32_f16(Af[1][2], Bh1a, D1, 0, 0, 0);
                D2 = __builtin_amdgcn_mfma_f32_16x16x32_f16(Af[2][2], Bh1a, D2, 0, 0, 0);
                D3 = __builtin_amdgcn_mfma_f32_16x16x32_f16(Af[3][2], Bh1a, D3, 0, 0, 0);
                A0 = __builtin_amdgcn_mfma_f32_16x16x32_f16(Af[0][1], Bh0b, A0, 0, 0, 0);
                A1 = __builtin_amdgcn_mfma_f32_16x16x32_f16(Af[1][1], Bh0b, A1, 0, 0, 0);
                A2 = __builtin_amdgcn_mfma_f32_16x16x32_f16(Af[2][1], Bh0b, A2, 0, 0, 0);
                A3 = __builtin_amdgcn_mfma_f32_16x16x32_f16(Af[3][1], Bh0b, A3, 0, 0, 0);
                D0 = __builtin_amdgcn_mfma_f32_16x16x32_f16(Af[0][3], Bh1b, D0, 0, 0, 0);
                D1 = __builtin_amdgcn_mfma_f32_16x16x32_f16(Af[1][3], Bh1b, D1, 0, 0, 0);
                D2 = __builtin_amdgcn_mfma_f32_16x16x32_f16(Af[2][3], Bh1b, D2, 0, 0, 0);
                D3 = __builtin_amdgcn_mfma_f32_16x16x32_f16(Af[3][3], Bh1b, D3, 0, 0, 0);
                const f32x4 C0 = A0 + D0, C1 = A1 + D1, C2 = A2 + D2, C3 = A3 + D3;
                half4 hh;
                #pragma unroll
                for (int r = 0; r < 4; ++r) {
                    float ig = sigmoid_f(C0[r]);
                    float fg = sigmoid_f(C1[r]);
                    float gg = tanh_f(C2[r]);
                    float og = sigmoid_f(C3[r]);
                    cst[r] = fg * cst[r] + ig * gg;
                    hh[r] = (_Float16)(og * tanh_f(cst[r]));
                }
                const uint2 hu = __builtin_bit_cast(uint2, hh);
                *reinterpret_cast<uint2*>(&B1[nxt][lmod][64 + hidx0]) = hu;
            }
        }

        xv1 = xnew;
        __syncthreads();
    }

    // ---- head. h1_last lives in B1[1], k 64-127 ----
    {
        const int un = tid & 15;
        const int uk0 = tid >> 4;         // 0..31; handles uk0 and uk0+32
        const int lid = line_id[b0 + un];
        #pragma unroll
        for (int hh = 0; hh < 2; ++hh) {
            const int u = uk0 + 32 * hh;
            float a = b1[u];
            #pragma unroll
            for (int j = 0; j < H; ++j)
                a = fmaf(w1[u * (H + 8) + j], (float)B1[1][un][64 + j], a);
            #pragma unroll
            for (int e = 0; e < 8; ++e)
                a = fmaf(w1[u * (H + 8) + H + e], embed[lid * 8 + e], a);
            fc1_lds[un][u] = fmaxf(a, 0.f);
        }
    }
    __syncthreads();
    if (tid < NBATCH * 5) {
        const int n2 = tid / 5, q = tid - 5 * n2;
        float o = b2[q];
        #pragma unroll
        for (int j = 0; j < H; ++j)
            o = fmaf(w2[q * H + j], fc1_lds[n2][j], o);
        out[(b0 + n2) * 5 + q] = o;
    }
}

extern "C" void kernel_launch(void* const* d_in, const int* in_sizes, int n_in,
                              void* d_out, int out_size, void* d_ws, size_t ws_size,
                              hipStream_t stream) {
    const float* seq     = (const float*)d_in[0];
    const int*   line_id = (const int*)  d_in[1];
    const float* embed   = (const float*)d_in[2];
    const float* w_ih0   = (const float*)d_in[3];
    const float* w_hh0   = (const float*)d_in[4];
    const float* b_ih0   = (const float*)d_in[5];
    const float* b_hh0   = (const float*)d_in[6];
    const float* w_ih1   = (const float*)d_in[7];
    const float* w_hh1   = (const float*)d_in[8];
    const float* b_ih1   = (const float*)d_in[9];
    const float* b_hh1   = (const float*)d_in[10];
    const float* w1      = (const float*)d_in[11];
    const float* b1      = (const float*)d_in[12];
    const float* w2      = (const float*)d_in[13];
    const float* b2      = (const float*)d_in[14];
    float* out = (float*)d_out;

    lstm_forecast_kernel<<<dim3(1024 / NBATCH), dim3(512), 0, stream>>>(
        seq, line_id, embed,
        w_ih0, w_hh0, b_ih0, b_hh0,
        w_ih1, w_hh1, b_ih1, b_hh1,
        w1, b1, w2, b2, out);
}